// Round 7
// baseline (495.893 us; speedup 1.0000x reference)
//
#include <hip/hip_runtime.h>
#include <hip/hip_bf16.h>

constexpr int Dd   = 512;
constexpr int Nn   = 1024;
constexpr int Ttok = 16384;              // B*L
constexpr float DECAYc = 0.99f;
constexpr float MARGIN = 10.0f;          // coarse err (bf16 inputs only) << 10
constexpr int CH = 16;                   // tokens per dw chunk

typedef short bf16x8 __attribute__((ext_vector_type(8)));
typedef float f32x4  __attribute__((ext_vector_type(4)));
typedef unsigned short us8v __attribute__((ext_vector_type(8)));

__device__ inline unsigned short f2bf(float f) {       // round-to-nearest-even
  unsigned int b = __float_as_uint(f);
  return (unsigned short)((b + 0x7FFFu + ((b >> 16) & 1u)) >> 16);
}

// ------------------------------------------- codebook -> bf16, plus csq[n]
__global__ __launch_bounds__(64) void k_prep_cb(const float* __restrict__ cb,
                                                unsigned short* __restrict__ cbh,
                                                float* __restrict__ csq) {
  const int n = blockIdx.x, l = threadIdx.x;
  const float4* r = (const float4*)(cb + (size_t)n * Dd);
  float4 a = r[l], b = r[l + 64];
  float ss = a.x*a.x + a.y*a.y + a.z*a.z + a.w*a.w
           + b.x*b.x + b.y*b.y + b.z*b.z + b.w*b.w;
  ushort4 ua, ub;
  ua.x = f2bf(a.x); ua.y = f2bf(a.y); ua.z = f2bf(a.z); ua.w = f2bf(a.w);
  ub.x = f2bf(b.x); ub.y = f2bf(b.y); ub.z = f2bf(b.z); ub.w = f2bf(b.w);
  ((ushort4*)(cbh + (size_t)n * Dd))[l]      = ua;
  ((ushort4*)(cbh + (size_t)n * Dd))[l + 64] = ub;
#pragma unroll
  for (int o = 32; o; o >>= 1) ss += __shfl_down(ss, o);
  if (l == 0) csq[n] = ss;
}

// ------------- MFMA GEMM with FUSED per-block top-2 argmin epilogue.
// Scores s[t][n] = csq[n] - 2*x.c (f32, never rounded). Per block
// (128 codes x 128 tokens): reduce to per-token (v0,i0,v1,i1,cnt) where
// cnt = #codes <= wave_v0+MARGIN (summed over the 2 code-halves).
// A (codebook) double-buffered in LDS, gload_lds for kc+1 issued during
// MFMA(kc) so the barrier drain no longer exposes full L2 latency.
__global__ __launch_bounds__(256) void k_gemm_scores(
    const unsigned short* __restrict__ cbh, const float* __restrict__ x,
    const float* __restrict__ csq, float4* __restrict__ part) {
  __shared__ unsigned short As[2][128 * 64];   // codes, double-buffered
  __shared__ unsigned short Bs[128 * 64];      // tokens
  __shared__ float4 red4[2][128];              // [wr][token]: v0,v1,i01,cnt
  const int tid = threadIdx.x;
  const int w = tid >> 6, l = tid & 63;
  const int b = blockIdx.x;
  const int s = (b & 7) * 128 + (b >> 3);      // XCD-aware bijective swizzle
  const int cm = s & 7;        // code-block  (M)
  const int tn = s >> 3;       // token-block (N)
  const int wr = w >> 1, wc = w & 1;

  const int srow = tid >> 3;                   // 0..31 staging row base
  const int xorw = (tid >> 3) & 7;             // row&7 of staged rows
  const int scolA = ((tid & 7) ^ xorw) * 8;    // A: swizzled global source
  const int scolB = (tid & 7) * 8;             // B: linear global chunk
  const int wcolB = ((tid & 7) ^ xorw) * 8;    // B: swizzled LDS write

  f32x4 acc[4][4] = {};

  const unsigned short* gA0 = cbh + (size_t)(cm * 128) * Dd;
  const float*          gB0 = x   + (size_t)(tn * 128) * Dd;

  us8v bq[4];
#define LOADB(KC) do {                                                        \
    const int k0_ = (KC) * 64;                                                \
    _Pragma("unroll")                                                         \
    for (int p = 0; p < 4; ++p) {                                             \
      const float* gb = gB0 + (size_t)(p * 32 + srow) * Dd + k0_ + scolB;     \
      float4 v0_ = *(const float4*)gb;                                        \
      float4 v1_ = *(const float4*)(gb + 4);                                  \
      us8v o;                                                                 \
      o[0]=f2bf(v0_.x); o[1]=f2bf(v0_.y); o[2]=f2bf(v0_.z); o[3]=f2bf(v0_.w); \
      o[4]=f2bf(v1_.x); o[5]=f2bf(v1_.y); o[6]=f2bf(v1_.z); o[7]=f2bf(v1_.w); \
      bq[p] = o;                                                              \
    }                                                                         \
  } while (0)
#define ISSUEA(KC, BUF) do {                                                  \
    const int k0_ = (KC) * 64;                                                \
    _Pragma("unroll")                                                         \
    for (int c = 0; c < 4; ++c) {                                             \
      const unsigned short* ga = gA0 + (size_t)(c * 32 + srow) * Dd + k0_ + scolA; \
      char* la = (char*)&As[BUF][0] + c * 4096 + w * 1024;                    \
      __builtin_amdgcn_global_load_lds((const __attribute__((address_space(1))) void*)ga, \
                                       (__attribute__((address_space(3))) void*)la, 16, 0, 0); \
    }                                                                         \
  } while (0)

  ISSUEA(0, 0);
  LOADB(0);

  for (int kc = 0; kc < Dd / 64; ++kc) {
    __syncthreads();      // (a) prev MFMA reads done; drains A(kc)/B(kc) vmem
#pragma unroll
    for (int p = 0; p < 4; ++p)
      *(us8v*)&Bs[(p * 32 + srow) * 64 + wcolB] = bq[p];
    __syncthreads();      // (b) tiles ready (no outstanding vmem here)
    if (kc + 1 < Dd / 64) {               // prefetch next under MFMA
      ISSUEA(kc + 1, (kc + 1) & 1);
      LOADB(kc + 1);
    }
    const unsigned short* Ab = &As[kc & 1][0];
#pragma unroll
    for (int ks = 0; ks < 2; ++ks) {
      const int ra = l & 15;
      const int rx = l & 7;
      const int kbs = ((ks * 4 + (l >> 4)) ^ rx) * 8;   // swizzled read chunk
      bf16x8 af[4], bfr[4];
#pragma unroll
      for (int m = 0; m < 4; ++m)
        af[m] = *(const bf16x8*)&Ab[(wr * 64 + m * 16 + ra) * 64 + kbs];
#pragma unroll
      for (int n = 0; n < 4; ++n)
        bfr[n] = *(const bf16x8*)&Bs[(wc * 64 + n * 16 + ra) * 64 + kbs];
#pragma unroll
      for (int m = 0; m < 4; ++m)
#pragma unroll
        for (int n = 0; n < 4; ++n)
          acc[m][n] = __builtin_amdgcn_mfma_f32_16x16x32_bf16(af[m], bfr[n], acc[m][n], 0, 0, 0);
    }
  }
#undef LOADB
#undef ISSUEA

  // ---------------- fused top-2 argmin epilogue ----------------
  const int base4 = wr * 64 + (l >> 4) * 4;      // lane's local code base
  float4 cs[4];
#pragma unroll
  for (int m = 0; m < 4; ++m)
    cs[m] = *(const float4*)&csq[cm * 128 + base4 + m * 16];

#pragma unroll
  for (int n = 0; n < 4; ++n) {
    float v0 = 3.4e38f, v1 = 3.4e38f;
    int i0 = 0x7fffffff, i1 = 0x7fffffff;
#pragma unroll
    for (int m = 0; m < 4; ++m) {
#pragma unroll
      for (int r = 0; r < 4; ++r) {
        float sv = fmaf(-2.0f, acc[m][n][r], ((const float*)&cs[m])[r]);
        int idx = cm * 128 + base4 + m * 16 + r;   // ascending within lane
        if (sv < v0)      { v1 = v0; i1 = i0; v0 = sv; i0 = idx; }
        else if (sv < v1) { v1 = sv; i1 = idx; }
      }
    }
    // merge top-2 across the 4 lanes (l^16, l^32) covering this wave's codes
#pragma unroll
    for (int o = 16; o <= 32; o <<= 1) {
      float b0 = __shfl_xor(v0, o), b1 = __shfl_xor(v1, o);
      int  bi0 = __shfl_xor(i0, o), bi1 = __shfl_xor(i1, o);
      bool bf = (b0 < v0) || (b0 == v0 && bi0 < i0);
      float lo = bf ? v0 : b0; int loi = bf ? i0 : bi0;   // loser of mins
      float w1 = bf ? b1 : v1; int w1i = bf ? bi1 : i1;   // winner's 2nd
      if (bf) { v0 = b0; i0 = bi0; }
      bool sf = (lo < w1) || (lo == w1 && loi < w1i);
      v1 = sf ? lo : w1; i1 = sf ? loi : w1i;
    }
    // margin count vs wave min (safe: global_min <= wave v0)
    int c16 = 0; const float thr = v0 + MARGIN;
#pragma unroll
    for (int m = 0; m < 4; ++m)
#pragma unroll
      for (int r = 0; r < 4; ++r)
        c16 += (fmaf(-2.0f, acc[m][n][r], ((const float*)&cs[m])[r]) <= thr) ? 1 : 0;
    c16 += __shfl_xor(c16, 16); c16 += __shfl_xor(c16, 32);
    if ((l >> 4) == 0)
      red4[wr][wc * 64 + n * 16 + l] = make_float4(
          v0, v1, __uint_as_float((unsigned)i0 | ((unsigned)i1 << 16)),
          __uint_as_float((unsigned)c16));
  }
  __syncthreads();
  if (tid < 128) {          // merge the two code-halves (wr=0,1) per token
    float4 a = red4[0][tid], e = red4[1][tid];
    unsigned au = __float_as_uint(a.z), eu = __float_as_uint(e.z);
    int ai0 = au & 0xffff, ai1 = au >> 16;
    int ei0 = eu & 0xffff, ei1 = eu >> 16;
    bool bf = (e.x < a.x) || (e.x == a.x && ei0 < ai0);
    float v0 = bf ? e.x : a.x; int i0 = bf ? ei0 : ai0;
    float lo = bf ? a.x : e.x; int loi = bf ? ai0 : ei0;
    float w1 = bf ? e.y : a.y; int w1i = bf ? ei1 : ai1;
    bool sf = (lo < w1) || (lo == w1 && loi < w1i);
    float v1 = sf ? lo : w1; int i1 = sf ? loi : w1i;
    unsigned cnt = __float_as_uint(a.w) + __float_as_uint(e.w);
    part[(size_t)cm * Ttok + tn * 128 + tid] = make_float4(
        v0, v1, __uint_as_float((unsigned)i0 | ((unsigned)i1 << 16)),
        __uint_as_float(cnt));
  }
}

// exact fp32 rescore of one code (wave-cooperative), uniform n
__device__ inline void rescore(int n, const float4& xa, const float4& xb,
                               const float* __restrict__ cb,
                               const float* __restrict__ csq, int l,
                               float& bestv, int& besti) {
  const float4* cr = (const float4*)(cb + (size_t)n * Dd);
  float4 ca = cr[l * 2], cc = cr[l * 2 + 1];
  float p = xa.x*ca.x + xa.y*ca.y + xa.z*ca.z + xa.w*ca.w
          + xb.x*cc.x + xb.y*cc.y + xb.z*cc.z + xb.w*cc.w;
#pragma unroll
  for (int o = 32; o; o >>= 1) p += __shfl_xor(p, o);
  float sc = csq[n] - 2.0f * p;
  if (sc < bestv || (sc == bestv && n < besti)) { bestv = sc; besti = n; }
}

// ---- per-token: merge 8 block partials, exact-rescore candidates.
// Correctness: any code within MARGIN of the global coarse min is either a
// stored top-2 of its block, or its block has cnt>2 -> full 128-code rescore.
__global__ __launch_bounds__(256) void k_select(
    const float4* __restrict__ part, const float* __restrict__ x,
    const float* __restrict__ cb, const float* __restrict__ csq,
    int* __restrict__ idxb, float* __restrict__ idxf, float* __restrict__ hist) {
  const int tid = threadIdx.x, wid = tid >> 6, l = tid & 63;
  const int t = blockIdx.x * 4 + wid;
  float v0 = 3.4e38f, v1 = 3.4e38f; unsigned ii = 0, cnt = 0;
  if (l < 8) {
    float4 e = part[(size_t)l * Ttok + t];
    v0 = e.x; v1 = e.y; ii = __float_as_uint(e.z); cnt = __float_as_uint(e.w);
  }
  float m = v0;
#pragma unroll
  for (int o = 1; o < 8; o <<= 1) m = fminf(m, __shfl_xor(m, o));
  m = __shfl(m, 0);
  const float thr = m + MARGIN;
  const float4* xr = (const float4*)(x + (size_t)t * Dd);
  float4 xa = xr[l * 2], xb = xr[l * 2 + 1];
  float bestv = 3.4e38f; int besti = 0x7fffffff;
  for (int b = 0; b < 8; ++b) {
    float vb0 = __shfl(v0, b);
    if (vb0 > thr) continue;
    unsigned cntb = __shfl(cnt, b);
    unsigned iib  = __shfl(ii, b);
    float vb1     = __shfl(v1, b);
    if (cntb <= 2) {
      rescore((int)(iib & 0xffff), xa, xb, cb, csq, l, bestv, besti);
      if (vb1 <= thr)
        rescore((int)(iib >> 16), xa, xb, cb, csq, l, bestv, besti);
    } else {                               // rare guaranteed-correct fallback
      for (int c = 0; c < 128; ++c)
        rescore(b * 128 + c, xa, xb, cb, csq, l, bestv, besti);
    }
  }
  if (l == 0) {
    idxb[t] = besti;
    idxf[t] = (float)besti;
    atomicAdd(&hist[besti], 1.0f);
  }
}

// ----------------- prefix sum of histogram (1 block, 256 thr, wave scan)
__global__ __launch_bounds__(256) void k_offsets(const float* __restrict__ hist,
                                                 int* __restrict__ offs,
                                                 int* __restrict__ cursor) {
  __shared__ int wsum[4];
  const int tid = threadIdx.x, l = tid & 63, wd = tid >> 6;
  const int base = tid * 4;
  int c0 = (int)hist[base], c1 = (int)hist[base + 1],
      c2 = (int)hist[base + 2], c3 = (int)hist[base + 3];
  int sum = c0 + c1 + c2 + c3;
  int sc = sum;
#pragma unroll
  for (int o = 1; o < 64; o <<= 1) { int v = __shfl_up(sc, o); if (l >= o) sc += v; }
  if (l == 63) wsum[wd] = sc;
  __syncthreads();
  int wbase = 0;
  for (int i = 0; i < wd; ++i) wbase += wsum[i];
  int e = wbase + sc - sum;
  offs[base] = e;     cursor[base] = e;
  offs[base+1] = e + c0; cursor[base+1] = e + c0;
  offs[base+2] = e + c0 + c1; cursor[base+2] = e + c0 + c1;
  offs[base+3] = e + c0 + c1 + c2; cursor[base+3] = e + c0 + c1 + c2;
}

// -------------------------------- bucket tokens by index (code-sorted order)
__global__ __launch_bounds__(256) void k_scatter(const int* __restrict__ idxb,
                                                 int* __restrict__ cursor,
                                                 int* __restrict__ bucket,
                                                 int* __restrict__ bcode) {
  int t = blockIdx.x * 256 + threadIdx.x;
  if (t < Ttok) {
    int n = idxb[t];
    int p = atomicAdd(&cursor[n], 1);
    bucket[p] = t;
    bcode[p] = n;
  }
}

// ------- load-balanced segmented sum: dw[n][d] += x rows of chunk segments
__global__ __launch_bounds__(512) void k_dw_part(
    const float* __restrict__ x, const int* __restrict__ bucket,
    const int* __restrict__ bcode, float* __restrict__ dw) {
  __shared__ int sh_t[CH], sh_n[CH];
  const int tid = threadIdx.x;
  const int p0 = blockIdx.x * CH;
  if (tid < CH) { sh_t[tid] = bucket[p0 + tid]; sh_n[tid] = bcode[p0 + tid]; }
  __syncthreads();
  float v[CH];
#pragma unroll
  for (int j = 0; j < CH; ++j)
    v[j] = x[(size_t)sh_t[j] * Dd + tid];
  float acc = v[0]; int cur = sh_n[0];
#pragma unroll
  for (int j = 1; j < CH; ++j) {
    int n = sh_n[j];
    if (n != cur) { atomicAdd(&dw[(size_t)cur * Dd + tid], acc); acc = 0.f; cur = n; }
    acc += v[j];
  }
  atomicAdd(&dw[(size_t)cur * Dd + tid], acc);
}

// -------- codebook_new = (decay*ema + (1-decay)*dw) / (decay*counts + (1-decay)*hist)
__global__ __launch_bounds__(256) void finalize_cb(
    const float* __restrict__ ema, const float* __restrict__ dw,
    const float* __restrict__ counts, const float* __restrict__ hist,
    float* __restrict__ cbnew) {
  int e4 = blockIdx.x * 256 + threadIdx.x;
  int n = e4 >> 7;
  float cnt = DECAYc * counts[n] + (1.0f - DECAYc) * hist[n];
  float inv = 1.0f / cnt;
  float4 e = ((const float4*)ema)[e4];
  float4 d = ((const float4*)dw)[e4];
  float4 o;
  o.x = (DECAYc * e.x + (1.0f - DECAYc) * d.x) * inv;
  o.y = (DECAYc * e.y + (1.0f - DECAYc) * d.y) * inv;
  o.z = (DECAYc * e.z + (1.0f - DECAYc) * d.z) * inv;
  o.w = (DECAYc * e.w + (1.0f - DECAYc) * d.w) * inv;
  ((float4*)cbnew)[e4] = o;
}

// ------- quantized = gather(cbnew, idx); loss partials. 4 independent
// float4s per thread so all loads are in flight (ILP, fixed in r6).
__global__ __launch_bounds__(256) void quant_loss(
    const float* __restrict__ x, const float* __restrict__ cbnew,
    const int* __restrict__ idx, float* __restrict__ out_q,
    float* __restrict__ loss) {
  const int e0 = blockIdx.x * 256 + threadIdx.x;
  const int gsz = 524288;                    // 2048 blocks * 256 threads
  int n[4]; float4 q[4], xv[4];
#pragma unroll
  for (int j = 0; j < 4; ++j) n[j] = idx[(e0 + j * gsz) >> 7];
#pragma unroll
  for (int j = 0; j < 4; ++j) {
    const int e = e0 + j * gsz;
    q[j]  = ((const float4*)(cbnew + (size_t)n[j] * Dd))[e & 127];
    xv[j] = ((const float4*)x)[e];
  }
  float part = 0.f;
#pragma unroll
  for (int j = 0; j < 4; ++j) {
    ((float4*)out_q)[e0 + j * gsz] = q[j];
    float dx = xv[j].x - q[j].x, dy = xv[j].y - q[j].y,
          dz = xv[j].z - q[j].z, dw_ = xv[j].w - q[j].w;
    part += dx*dx + dy*dy + dz*dz + dw_*dw_;
  }
  __shared__ float red[4];
#pragma unroll
  for (int o = 32; o; o >>= 1) part += __shfl_down(part, o);
  int wid = threadIdx.x >> 6, lane = threadIdx.x & 63;
  if (lane == 0) red[wid] = part;
  __syncthreads();
  if (threadIdx.x == 0) atomicAdd(loss, red[0] + red[1] + red[2] + red[3]);
}

__global__ void loss_final(const float* __restrict__ loss,
                           float* __restrict__ out_loss) {
  *out_loss = loss[0] * (0.5f / (float)((size_t)Ttok * Dd));
}

// ---------------------------------------------------------------- launch
extern "C" void kernel_launch(void* const* d_in, const int* in_sizes, int n_in,
                              void* d_out, int out_size, void* d_ws, size_t ws_size,
                              hipStream_t stream) {
  const float* x      = (const float*)d_in[0];
  const float* cb     = (const float*)d_in[1];
  const float* ema    = (const float*)d_in[2];
  const float* counts = (const float*)d_in[3];

  float* out      = (float*)d_out;
  float* q_out    = out;
  float* loss_out = out + (size_t)Ttok * Dd;
  float* idxf_out = loss_out + 1;
  // per-block argmin partials (float4 [8][16384] = 2 MB) alias q_out's head;
  // fully consumed by k_select before quant_loss overwrites q_out.
  float4* part = (float4*)q_out;

  // workspace layout (float offsets) — same as r6 (proven)
  float* ws = (float*)d_ws;
  unsigned short* cbh = (unsigned short*)ws;           // [0, 262144)  bf16 cb
  float* dw      = ws + 262144;                        // 524288 (zeroed)
  float* hist    = ws + 786432;                        // 1024   (zeroed)
  float* loss    = ws + 787456;                        // 4      (zeroed)
  float* csq     = ws + 787460;                        // 1024
  int*   offs    = (int*)(ws + 788484);                // 1024
  int*   cursor  = (int*)(ws + 789508);                // 1024
  int*   bucket  = (int*)(ws + 790532);                // 16384
  int*   bcode   = (int*)(ws + 806916);                // 16384
  int*   idxb    = (int*)(ws + 823300);                // 16384
  float* cbnew   = ws + 839684;                        // 524288 -> ends 1363972

  // zero dw + hist + loss (contiguous) every call
  hipMemsetAsync(dw, 0, (size_t)525316 * sizeof(float), stream);

  k_prep_cb<<<Nn, 64, 0, stream>>>(cb, cbh, csq);
  k_gemm_scores<<<(Nn / 128) * (Ttok / 128), 256, 0, stream>>>(cbh, x, csq, part);
  k_select<<<Ttok / 4, 256, 0, stream>>>(part, x, cb, csq, idxb, idxf_out, hist);
  k_offsets<<<1, 256, 0, stream>>>(hist, offs, cursor);
  k_scatter<<<Ttok / 256, 256, 0, stream>>>(idxb, cursor, bucket, bcode);
  k_dw_part<<<Ttok / CH, 512, 0, stream>>>(x, bucket, bcode, dw);
  finalize_cb<<<(Nn * Dd / 4) / 256, 256, 0, stream>>>(ema, dw, counts, hist, cbnew);
  quant_loss<<<2048, 256, 0, stream>>>(x, cbnew, idxb, q_out, loss);
  loss_final<<<1, 1, 0, stream>>>(loss, loss_out);
}

// Round 8
// 152.198 us; speedup vs baseline: 3.2582x; 3.2582x over previous
//
#include <hip/hip_runtime.h>
#include <hip/hip_bf16.h>

constexpr int Dd   = 512;
constexpr int Nn   = 1024;
constexpr int Ttok = 16384;              // B*L
constexpr float DECAYc = 0.99f;
// Coarse scores are exact-f32 MFMA of bf16-rounded inputs: error std ~0.05.
// MARGIN=2.0 is >40 sigma; fallback (cnt>2 within a 64-code half) is rare.
constexpr float MARGIN = 2.0f;
constexpr int CH = 16;                   // tokens per dw chunk

typedef short bf16x8 __attribute__((ext_vector_type(8)));
typedef float f32x4  __attribute__((ext_vector_type(4)));
typedef unsigned short us8v __attribute__((ext_vector_type(8)));

__device__ inline unsigned short f2bf(float f) {       // round-to-nearest-even
  unsigned int b = __float_as_uint(f);
  return (unsigned short)((b + 0x7FFFu + ((b >> 16) & 1u)) >> 16);
}

// ------------------------------------------- codebook -> bf16, plus csq[n]
__global__ __launch_bounds__(64) void k_prep_cb(const float* __restrict__ cb,
                                                unsigned short* __restrict__ cbh,
                                                float* __restrict__ csq) {
  const int n = blockIdx.x, l = threadIdx.x;
  const float4* r = (const float4*)(cb + (size_t)n * Dd);
  float4 a = r[l], b = r[l + 64];
  float ss = a.x*a.x + a.y*a.y + a.z*a.z + a.w*a.w
           + b.x*b.x + b.y*b.y + b.z*b.z + b.w*b.w;
  ushort4 ua, ub;
  ua.x = f2bf(a.x); ua.y = f2bf(a.y); ua.z = f2bf(a.z); ua.w = f2bf(a.w);
  ub.x = f2bf(b.x); ub.y = f2bf(b.y); ub.z = f2bf(b.z); ub.w = f2bf(b.w);
  ((ushort4*)(cbh + (size_t)n * Dd))[l]      = ua;
  ((ushort4*)(cbh + (size_t)n * Dd))[l + 64] = ub;
#pragma unroll
  for (int o = 32; o; o >>= 1) ss += __shfl_down(ss, o);
  if (l == 0) csq[n] = ss;
}

// ------------- MFMA GEMM with FUSED per-64-code-half top-2 argmin epilogue.
// Scores s[t][n] = csq[n] - 2*x.c (f32, never rounded). Each wave owns a
// 64-code half x 64 tokens; per token it emits (v0,v1,i0|i1,cnt) where
// cnt = #codes in the half <= half_v0 + MARGIN. 16 slots per token total.
__global__ __launch_bounds__(256) void k_gemm_scores(
    const unsigned short* __restrict__ cbh, const float* __restrict__ x,
    const float* __restrict__ csq, float4* __restrict__ part) {
  __shared__ unsigned short As[2][128 * 64];   // codes, double-buffered
  __shared__ unsigned short Bs[128 * 64];      // tokens
  const int tid = threadIdx.x;
  const int w = tid >> 6, l = tid & 63;
  const int b = blockIdx.x;
  const int s = (b & 7) * 128 + (b >> 3);      // XCD-aware bijective swizzle
  const int cm = s & 7;        // code-block  (M)
  const int tn = s >> 3;       // token-block (N)
  const int wr = w >> 1, wc = w & 1;

  const int srow = tid >> 3;                   // 0..31 staging row base
  const int xorw = (tid >> 3) & 7;             // row&7 of staged rows
  const int scolA = ((tid & 7) ^ xorw) * 8;    // A: swizzled global source
  const int scolB = (tid & 7) * 8;             // B: linear global chunk
  const int wcolB = ((tid & 7) ^ xorw) * 8;    // B: swizzled LDS write

  f32x4 acc[4][4] = {};

  const unsigned short* gA0 = cbh + (size_t)(cm * 128) * Dd;
  const float*          gB0 = x   + (size_t)(tn * 128) * Dd;

  us8v bq[4];
#define LOADB(KC) do {                                                        \
    const int k0_ = (KC) * 64;                                                \
    _Pragma("unroll")                                                         \
    for (int p = 0; p < 4; ++p) {                                             \
      const float* gb = gB0 + (size_t)(p * 32 + srow) * Dd + k0_ + scolB;     \
      float4 v0_ = *(const float4*)gb;                                        \
      float4 v1_ = *(const float4*)(gb + 4);                                  \
      us8v o;                                                                 \
      o[0]=f2bf(v0_.x); o[1]=f2bf(v0_.y); o[2]=f2bf(v0_.z); o[3]=f2bf(v0_.w); \
      o[4]=f2bf(v1_.x); o[5]=f2bf(v1_.y); o[6]=f2bf(v1_.z); o[7]=f2bf(v1_.w); \
      bq[p] = o;                                                              \
    }                                                                         \
  } while (0)
#define ISSUEA(KC, BUF) do {                                                  \
    const int k0_ = (KC) * 64;                                                \
    _Pragma("unroll")                                                         \
    for (int c = 0; c < 4; ++c) {                                             \
      const unsigned short* ga = gA0 + (size_t)(c * 32 + srow) * Dd + k0_ + scolA; \
      char* la = (char*)&As[BUF][0] + c * 4096 + w * 1024;                    \
      __builtin_amdgcn_global_load_lds((const __attribute__((address_space(1))) void*)ga, \
                                       (__attribute__((address_space(3))) void*)la, 16, 0, 0); \
    }                                                                         \
  } while (0)

  ISSUEA(0, 0);
  LOADB(0);

  for (int kc = 0; kc < Dd / 64; ++kc) {
    __syncthreads();      // (a) prev MFMA reads done; drains A(kc)/B(kc) vmem
#pragma unroll
    for (int p = 0; p < 4; ++p)
      *(us8v*)&Bs[(p * 32 + srow) * 64 + wcolB] = bq[p];
    __syncthreads();      // (b) tiles ready
    if (kc + 1 < Dd / 64) {               // prefetch next under MFMA
      ISSUEA(kc + 1, (kc + 1) & 1);
      LOADB(kc + 1);
    }
    const unsigned short* Ab = &As[kc & 1][0];
#pragma unroll
    for (int ks = 0; ks < 2; ++ks) {
      const int ra = l & 15;
      const int rx = l & 7;
      const int kbs = ((ks * 4 + (l >> 4)) ^ rx) * 8;   // swizzled read chunk
      bf16x8 af[4], bfr[4];
#pragma unroll
      for (int m = 0; m < 4; ++m)
        af[m] = *(const bf16x8*)&Ab[(wr * 64 + m * 16 + ra) * 64 + kbs];
#pragma unroll
      for (int n = 0; n < 4; ++n)
        bfr[n] = *(const bf16x8*)&Bs[(wc * 64 + n * 16 + ra) * 64 + kbs];
#pragma unroll
      for (int m = 0; m < 4; ++m)
#pragma unroll
        for (int n = 0; n < 4; ++n)
          acc[m][n] = __builtin_amdgcn_mfma_f32_16x16x32_bf16(af[m], bfr[n], acc[m][n], 0, 0, 0);
    }
  }
#undef LOADB
#undef ISSUEA

  // ------- fused per-half top-2 epilogue (no cross-half merge needed) -------
  const int base4 = wr * 64 + (l >> 4) * 4;      // lane's local code base
  float4 cs[4];
#pragma unroll
  for (int m = 0; m < 4; ++m)
    cs[m] = *(const float4*)&csq[cm * 128 + base4 + m * 16];

  const int slot = cm * 2 + wr;                  // 0..15
  const int tok0 = tn * 128 + wc * 64 + (l & 15);

#pragma unroll
  for (int n = 0; n < 4; ++n) {
    float v0 = 3.4e38f, v1 = 3.4e38f;
    int i0 = 0x7fffffff, i1 = 0x7fffffff;
#pragma unroll
    for (int m = 0; m < 4; ++m) {
#pragma unroll
      for (int r = 0; r < 4; ++r) {
        float sv = fmaf(-2.0f, acc[m][n][r], ((const float*)&cs[m])[r]);
        int idx = cm * 128 + base4 + m * 16 + r;
        if (sv < v0)      { v1 = v0; i1 = i0; v0 = sv; i0 = idx; }
        else if (sv < v1) { v1 = sv; i1 = idx; }
      }
    }
    // merge top-2 across the 4 lanes (l^16, l^32) holding this token's half
#pragma unroll
    for (int o = 16; o <= 32; o <<= 1) {
      float b0 = __shfl_xor(v0, o), b1 = __shfl_xor(v1, o);
      int  bi0 = __shfl_xor(i0, o), bi1 = __shfl_xor(i1, o);
      bool bf = (b0 < v0) || (b0 == v0 && bi0 < i0);
      float lo = bf ? v0 : b0; int loi = bf ? i0 : bi0;   // loser of mins
      float w1 = bf ? b1 : v1; int w1i = bf ? bi1 : i1;   // winner's 2nd
      if (bf) { v0 = b0; i0 = bi0; }
      bool sf = (lo < w1) || (lo == w1 && loi < w1i);
      v1 = sf ? lo : w1; i1 = sf ? loi : w1i;
    }
    // margin count vs half min (conservative: half_v0 >= global min)
    int c16 = 0; const float thr = v0 + MARGIN;
#pragma unroll
    for (int m = 0; m < 4; ++m)
#pragma unroll
      for (int r = 0; r < 4; ++r)
        c16 += (fmaf(-2.0f, acc[m][n][r], ((const float*)&cs[m])[r]) <= thr) ? 1 : 0;
    c16 += __shfl_xor(c16, 16); c16 += __shfl_xor(c16, 32);
    if ((l >> 4) == 0)
      part[(size_t)slot * Ttok + tok0 + n * 16] = make_float4(
          v0, v1, __uint_as_float((unsigned)i0 | ((unsigned)i1 << 16)),
          __uint_as_float((unsigned)c16));
  }
}

// exact fp32 rescore of one code (wave-cooperative), uniform n
__device__ inline void rescore(int n, const float4& xa, const float4& xb,
                               const float* __restrict__ cb,
                               const float* __restrict__ csq, int l,
                               float& bestv, int& besti) {
  const float4* cr = (const float4*)(cb + (size_t)n * Dd);
  float4 ca = cr[l * 2], cc = cr[l * 2 + 1];
  float p = xa.x*ca.x + xa.y*ca.y + xa.z*ca.z + xa.w*ca.w
          + xb.x*cc.x + xb.y*cc.y + xb.z*cc.z + xb.w*cc.w;
#pragma unroll
  for (int o = 32; o; o >>= 1) p += __shfl_xor(p, o);
  float sc = csq[n] - 2.0f * p;
  if (sc < bestv || (sc == bestv && n < besti)) { bestv = sc; besti = n; }
}

// ---- per-token: merge 16 half partials, exact-rescore candidates.
// Any code with coarse score <= globalmin+MARGIN is either a stored top-2 of
// its half, or that half has cnt>2 -> full 64-code rescore (rare).
__global__ __launch_bounds__(256) void k_select(
    const float4* __restrict__ part, const float* __restrict__ x,
    const float* __restrict__ cb, const float* __restrict__ csq,
    int* __restrict__ idxb, float* __restrict__ idxf, float* __restrict__ hist) {
  const int tid = threadIdx.x, wid = tid >> 6, l = tid & 63;
  const int t = blockIdx.x * 4 + wid;
  float v0 = 3.4e38f, v1 = 3.4e38f; unsigned ii = 0, cnt = 0;
  if (l < 16) {
    float4 e = part[(size_t)l * Ttok + t];
    v0 = e.x; v1 = e.y; ii = __float_as_uint(e.z); cnt = __float_as_uint(e.w);
  }
  float m = v0;
#pragma unroll
  for (int o = 1; o < 16; o <<= 1) m = fminf(m, __shfl_xor(m, o));
  m = __shfl(m, 0);
  const float thr = m + MARGIN;
  const float4* xr = (const float4*)(x + (size_t)t * Dd);
  float4 xa = xr[l * 2], xb = xr[l * 2 + 1];
  float bestv = 3.4e38f; int besti = 0x7fffffff;
  for (int b = 0; b < 16; ++b) {
    float vb0 = __shfl(v0, b);
    if (vb0 > thr) continue;
    unsigned cntb = __shfl(cnt, b);
    unsigned iib  = __shfl(ii, b);
    float vb1     = __shfl(v1, b);
    if (cntb <= 2) {
      rescore((int)(iib & 0xffff), xa, xb, cb, csq, l, bestv, besti);
      if (vb1 <= thr)
        rescore((int)(iib >> 16), xa, xb, cb, csq, l, bestv, besti);
    } else {                               // rare guaranteed-correct fallback
      for (int c = 0; c < 64; ++c)
        rescore(b * 64 + c, xa, xb, cb, csq, l, bestv, besti);
    }
  }
  if (l == 0) {
    idxb[t] = besti;
    idxf[t] = (float)besti;
    atomicAdd(&hist[besti], 1.0f);
  }
}

// ----------------- prefix sum of histogram (1 block, 256 thr, wave scan)
__global__ __launch_bounds__(256) void k_offsets(const float* __restrict__ hist,
                                                 int* __restrict__ offs,
                                                 int* __restrict__ cursor) {
  __shared__ int wsum[4];
  const int tid = threadIdx.x, l = tid & 63, wd = tid >> 6;
  const int base = tid * 4;
  int c0 = (int)hist[base], c1 = (int)hist[base + 1],
      c2 = (int)hist[base + 2], c3 = (int)hist[base + 3];
  int sum = c0 + c1 + c2 + c3;
  int sc = sum;
#pragma unroll
  for (int o = 1; o < 64; o <<= 1) { int v = __shfl_up(sc, o); if (l >= o) sc += v; }
  if (l == 63) wsum[wd] = sc;
  __syncthreads();
  int wbase = 0;
  for (int i = 0; i < wd; ++i) wbase += wsum[i];
  int e = wbase + sc - sum;
  offs[base] = e;     cursor[base] = e;
  offs[base+1] = e + c0; cursor[base+1] = e + c0;
  offs[base+2] = e + c0 + c1; cursor[base+2] = e + c0 + c1;
  offs[base+3] = e + c0 + c1 + c2; cursor[base+3] = e + c0 + c1 + c2;
}

// -------------------------------- bucket tokens by index (code-sorted order)
__global__ __launch_bounds__(256) void k_scatter(const int* __restrict__ idxb,
                                                 int* __restrict__ cursor,
                                                 int* __restrict__ bucket,
                                                 int* __restrict__ bcode) {
  int t = blockIdx.x * 256 + threadIdx.x;
  if (t < Ttok) {
    int n = idxb[t];
    int p = atomicAdd(&cursor[n], 1);
    bucket[p] = t;
    bcode[p] = n;
  }
}

// ------- load-balanced segmented sum: dw[n][d] += x rows of chunk segments
__global__ __launch_bounds__(512) void k_dw_part(
    const float* __restrict__ x, const int* __restrict__ bucket,
    const int* __restrict__ bcode, float* __restrict__ dw) {
  __shared__ int sh_t[CH], sh_n[CH];
  const int tid = threadIdx.x;
  const int p0 = blockIdx.x * CH;
  if (tid < CH) { sh_t[tid] = bucket[p0 + tid]; sh_n[tid] = bcode[p0 + tid]; }
  __syncthreads();
  float v[CH];
#pragma unroll
  for (int j = 0; j < CH; ++j)
    v[j] = x[(size_t)sh_t[j] * Dd + tid];
  float acc = v[0]; int cur = sh_n[0];
#pragma unroll
  for (int j = 1; j < CH; ++j) {
    int n = sh_n[j];
    if (n != cur) { atomicAdd(&dw[(size_t)cur * Dd + tid], acc); acc = 0.f; cur = n; }
    acc += v[j];
  }
  atomicAdd(&dw[(size_t)cur * Dd + tid], acc);
}

// -------- codebook_new = (decay*ema + (1-decay)*dw) / (decay*counts + (1-decay)*hist)
__global__ __launch_bounds__(256) void finalize_cb(
    const float* __restrict__ ema, const float* __restrict__ dw,
    const float* __restrict__ counts, const float* __restrict__ hist,
    float* __restrict__ cbnew) {
  int e4 = blockIdx.x * 256 + threadIdx.x;
  int n = e4 >> 7;
  float cnt = DECAYc * counts[n] + (1.0f - DECAYc) * hist[n];
  float inv = 1.0f / cnt;
  float4 e = ((const float4*)ema)[e4];
  float4 d = ((const float4*)dw)[e4];
  float4 o;
  o.x = (DECAYc * e.x + (1.0f - DECAYc) * d.x) * inv;
  o.y = (DECAYc * e.y + (1.0f - DECAYc) * d.y) * inv;
  o.z = (DECAYc * e.z + (1.0f - DECAYc) * d.z) * inv;
  o.w = (DECAYc * e.w + (1.0f - DECAYc) * d.w) * inv;
  ((float4*)cbnew)[e4] = o;
}

// ------- quantized = gather(cbnew, idx); loss partials. 4 independent
// float4s per thread so all loads are in flight (ILP, fixed in r6).
__global__ __launch_bounds__(256) void quant_loss(
    const float* __restrict__ x, const float* __restrict__ cbnew,
    const int* __restrict__ idx, float* __restrict__ out_q,
    float* __restrict__ loss) {
  const int e0 = blockIdx.x * 256 + threadIdx.x;
  const int gsz = 524288;                    // 2048 blocks * 256 threads
  int n[4]; float4 q[4], xv[4];
#pragma unroll
  for (int j = 0; j < 4; ++j) n[j] = idx[(e0 + j * gsz) >> 7];
#pragma unroll
  for (int j = 0; j < 4; ++j) {
    const int e = e0 + j * gsz;
    q[j]  = ((const float4*)(cbnew + (size_t)n[j] * Dd))[e & 127];
    xv[j] = ((const float4*)x)[e];
  }
  float part = 0.f;
#pragma unroll
  for (int j = 0; j < 4; ++j) {
    ((float4*)out_q)[e0 + j * gsz] = q[j];
    float dx = xv[j].x - q[j].x, dy = xv[j].y - q[j].y,
          dz = xv[j].z - q[j].z, dw_ = xv[j].w - q[j].w;
    part += dx*dx + dy*dy + dz*dz + dw_*dw_;
  }
  __shared__ float red[4];
#pragma unroll
  for (int o = 32; o; o >>= 1) part += __shfl_down(part, o);
  int wid = threadIdx.x >> 6, lane = threadIdx.x & 63;
  if (lane == 0) red[wid] = part;
  __syncthreads();
  if (threadIdx.x == 0) atomicAdd(loss, red[0] + red[1] + red[2] + red[3]);
}

__global__ void loss_final(const float* __restrict__ loss,
                           float* __restrict__ out_loss) {
  *out_loss = loss[0] * (0.5f / (float)((size_t)Ttok * Dd));
}

// ---------------------------------------------------------------- launch
extern "C" void kernel_launch(void* const* d_in, const int* in_sizes, int n_in,
                              void* d_out, int out_size, void* d_ws, size_t ws_size,
                              hipStream_t stream) {
  const float* x      = (const float*)d_in[0];
  const float* cb     = (const float*)d_in[1];
  const float* ema    = (const float*)d_in[2];
  const float* counts = (const float*)d_in[3];

  float* out      = (float*)d_out;
  float* q_out    = out;
  float* loss_out = out + (size_t)Ttok * Dd;
  float* idxf_out = loss_out + 1;
  // per-half argmin partials (float4 [16][16384] = 4 MB) alias q_out's head;
  // fully consumed by k_select before quant_loss overwrites q_out.
  float4* part = (float4*)q_out;

  // workspace layout (float offsets) — same as r6/r7 (proven)
  float* ws = (float*)d_ws;
  unsigned short* cbh = (unsigned short*)ws;           // [0, 262144)  bf16 cb
  float* dw      = ws + 262144;                        // 524288 (zeroed)
  float* hist    = ws + 786432;                        // 1024   (zeroed)
  float* loss    = ws + 787456;                        // 4      (zeroed)
  float* csq     = ws + 787460;                        // 1024
  int*   offs    = (int*)(ws + 788484);                // 1024
  int*   cursor  = (int*)(ws + 789508);                // 1024
  int*   bucket  = (int*)(ws + 790532);                // 16384
  int*   bcode   = (int*)(ws + 806916);                // 16384
  int*   idxb    = (int*)(ws + 823300);                // 16384
  float* cbnew   = ws + 839684;                        // 524288 -> ends 1363972

  // zero dw + hist + loss (contiguous) every call
  hipMemsetAsync(dw, 0, (size_t)525316 * sizeof(float), stream);

  k_prep_cb<<<Nn, 64, 0, stream>>>(cb, cbh, csq);
  k_gemm_scores<<<(Nn / 128) * (Ttok / 128), 256, 0, stream>>>(cbh, x, csq, part);
  k_select<<<Ttok / 4, 256, 0, stream>>>(part, x, cb, csq, idxb, idxf_out, hist);
  k_offsets<<<1, 256, 0, stream>>>(hist, offs, cursor);
  k_scatter<<<Ttok / 256, 256, 0, stream>>>(idxb, cursor, bucket, bcode);
  k_dw_part<<<Ttok / CH, 512, 0, stream>>>(x, bucket, bcode, dw);
  finalize_cb<<<(Nn * Dd / 4) / 256, 256, 0, stream>>>(ema, dw, counts, hist, cbnew);
  quant_loss<<<2048, 256, 0, stream>>>(x, cbnew, idxb, q_out, loss);
  loss_final<<<1, 1, 0, stream>>>(loss, loss_out);
}

// Round 9
// 131.612 us; speedup vs baseline: 3.7678x; 1.1564x over previous
//
#include <hip/hip_runtime.h>
#include <hip/hip_bf16.h>

constexpr int Dd   = 512;
constexpr int Nn   = 1024;
constexpr int Ttok = 16384;              // B*L
constexpr float DECAYc = 0.99f;
// Coarse scores are f32 MFMA of bf16-rounded inputs: error std ~0.07,
// worst plausible ~1.5. GAP=3.0 on the EXACT coarse runner-up (top-3 store
// makes g1 exact) is ~42 sigma.
constexpr float GAP = 3.0f;
constexpr int CH = 16;                   // tokens per dw chunk

typedef short bf16x8 __attribute__((ext_vector_type(8)));
typedef float f32x4  __attribute__((ext_vector_type(4)));
typedef unsigned short us8v __attribute__((ext_vector_type(8)));

__device__ inline unsigned short f2bf(float f) {       // round-to-nearest-even
  unsigned int b = __float_as_uint(f);
  return (unsigned short)((b + 0x7FFFu + ((b >> 16) & 1u)) >> 16);
}
__device__ inline unsigned cvtpk(float lo, float hi) { // 2xf32 -> packed bf16
  unsigned r;
  asm("v_cvt_pk_bf16_f32 %0, %1, %2" : "=v"(r) : "v"(lo), "v"(hi));
  return r;
}

// ------------------------------------------- codebook -> bf16, plus csq[n]
__global__ __launch_bounds__(64) void k_prep_cb(const float* __restrict__ cb,
                                                unsigned short* __restrict__ cbh,
                                                float* __restrict__ csq) {
  const int n = blockIdx.x, l = threadIdx.x;
  const float4* r = (const float4*)(cb + (size_t)n * Dd);
  float4 a = r[l], b = r[l + 64];
  float ss = a.x*a.x + a.y*a.y + a.z*a.z + a.w*a.w
           + b.x*b.x + b.y*b.y + b.z*b.z + b.w*b.w;
  ushort4 ua, ub;
  ua.x = f2bf(a.x); ua.y = f2bf(a.y); ua.z = f2bf(a.z); ua.w = f2bf(a.w);
  ub.x = f2bf(b.x); ub.y = f2bf(b.y); ub.z = f2bf(b.z); ub.w = f2bf(b.w);
  ((ushort4*)(cbh + (size_t)n * Dd))[l]      = ua;
  ((ushort4*)(cbh + (size_t)n * Dd))[l + 64] = ub;
#pragma unroll
  for (int o = 32; o; o >>= 1) ss += __shfl_down(ss, o);
  if (l == 0) csq[n] = ss;
}

// ------------- MFMA GEMM with FUSED per-64-code-half top-3 argmin epilogue.
// Each wave owns a 64-code half x 64 tokens; per token it emits
// (v0, v1, i0|i1, v2) — top-3 coarse values, indices for top-2.
__global__ __launch_bounds__(256) void k_gemm_scores(
    const unsigned short* __restrict__ cbh, const float* __restrict__ x,
    const float* __restrict__ csq, float4* __restrict__ part) {
  __shared__ unsigned short As[2][128 * 64];   // codes, double-buffered
  __shared__ unsigned short Bs[128 * 64];      // tokens
  const int tid = threadIdx.x;
  const int w = tid >> 6, l = tid & 63;
  const int b = blockIdx.x;
  const int s = (b & 7) * 128 + (b >> 3);      // XCD-aware bijective swizzle
  const int cm = s & 7;        // code-block  (M)
  const int tn = s >> 3;       // token-block (N)
  const int wr = w >> 1, wc = w & 1;

  const int srow = tid >> 3;                   // 0..31 staging row base
  const int xorw = (tid >> 3) & 7;             // row&7 of staged rows
  const int scolA = ((tid & 7) ^ xorw) * 8;    // A: swizzled global source
  const int scolB = (tid & 7) * 8;             // B: linear global chunk
  const int wcolB = ((tid & 7) ^ xorw) * 8;    // B: swizzled LDS write

  f32x4 acc[4][4] = {};

  const unsigned short* gA0 = cbh + (size_t)(cm * 128) * Dd;
  const float*          gB0 = x   + (size_t)(tn * 128) * Dd;

  uint4 bq[4];
#define LOADB(KC) do {                                                        \
    const int k0_ = (KC) * 64;                                                \
    _Pragma("unroll")                                                         \
    for (int p = 0; p < 4; ++p) {                                             \
      const float* gb = gB0 + (size_t)(p * 32 + srow) * Dd + k0_ + scolB;     \
      float4 v0_ = *(const float4*)gb;                                        \
      float4 v1_ = *(const float4*)(gb + 4);                                  \
      bq[p].x = cvtpk(v0_.x, v0_.y); bq[p].y = cvtpk(v0_.z, v0_.w);           \
      bq[p].z = cvtpk(v1_.x, v1_.y); bq[p].w = cvtpk(v1_.z, v1_.w);           \
    }                                                                         \
  } while (0)
#define ISSUEA(KC, BUF) do {                                                  \
    const int k0_ = (KC) * 64;                                                \
    _Pragma("unroll")                                                         \
    for (int c = 0; c < 4; ++c) {                                             \
      const unsigned short* ga = gA0 + (size_t)(c * 32 + srow) * Dd + k0_ + scolA; \
      char* la = (char*)&As[BUF][0] + c * 4096 + w * 1024;                    \
      __builtin_amdgcn_global_load_lds((const __attribute__((address_space(1))) void*)ga, \
                                       (__attribute__((address_space(3))) void*)la, 16, 0, 0); \
    }                                                                         \
  } while (0)

  ISSUEA(0, 0);
  LOADB(0);

  for (int kc = 0; kc < Dd / 64; ++kc) {
    __syncthreads();      // (a) prev MFMA reads done; drains A(kc)/B(kc) vmem
#pragma unroll
    for (int p = 0; p < 4; ++p)
      *(uint4*)&Bs[(p * 32 + srow) * 64 + wcolB] = bq[p];
    __syncthreads();      // (b) tiles ready
    if (kc + 1 < Dd / 64) {               // prefetch next under MFMA
      ISSUEA(kc + 1, (kc + 1) & 1);
      LOADB(kc + 1);
    }
    const unsigned short* Ab = &As[kc & 1][0];
#pragma unroll
    for (int ks = 0; ks < 2; ++ks) {
      const int ra = l & 15;
      const int rx = l & 7;
      const int kbs = ((ks * 4 + (l >> 4)) ^ rx) * 8;   // swizzled read chunk
      bf16x8 af[4], bfr[4];
#pragma unroll
      for (int m = 0; m < 4; ++m)
        af[m] = *(const bf16x8*)&Ab[(wr * 64 + m * 16 + ra) * 64 + kbs];
#pragma unroll
      for (int n = 0; n < 4; ++n)
        bfr[n] = *(const bf16x8*)&Bs[(wc * 64 + n * 16 + ra) * 64 + kbs];
#pragma unroll
      for (int m = 0; m < 4; ++m)
#pragma unroll
        for (int n = 0; n < 4; ++n)
          acc[m][n] = __builtin_amdgcn_mfma_f32_16x16x32_bf16(af[m], bfr[n], acc[m][n], 0, 0, 0);
    }
  }
#undef LOADB
#undef ISSUEA

  // ------- fused per-half top-3 epilogue -------
  const int base4 = wr * 64 + (l >> 4) * 4;      // lane's local code base
  float4 cs[4];
#pragma unroll
  for (int m = 0; m < 4; ++m)
    cs[m] = *(const float4*)&csq[cm * 128 + base4 + m * 16];

  const int slot = cm * 2 + wr;                  // 0..15
  const int tok0 = tn * 128 + wc * 64 + (l & 15);

#pragma unroll
  for (int n = 0; n < 4; ++n) {
    float v0 = 3.4e38f, v1 = 3.4e38f, v2 = 3.4e38f;
    int i0 = 0x7fffffff, i1 = 0x7fffffff;
#pragma unroll
    for (int m = 0; m < 4; ++m) {
#pragma unroll
      for (int r = 0; r < 4; ++r) {
        float sv = fmaf(-2.0f, acc[m][n][r], ((const float*)&cs[m])[r]);
        int idx = cm * 128 + base4 + m * 16 + r;
        if (sv < v0)      { v2 = v1; v1 = v0; i1 = i0; v0 = sv; i0 = idx; }
        else if (sv < v1) { v2 = v1; v1 = sv; i1 = idx; }
        else if (sv < v2) { v2 = sv; }
      }
    }
    // merge top-3 across the 4 lanes (l^16, l^32) holding this token's half
#pragma unroll
    for (int o = 16; o <= 32; o <<= 1) {
      float w0 = __shfl_xor(v0, o), w1 = __shfl_xor(v1, o), w2 = __shfl_xor(v2, o);
      int  j0 = __shfl_xor(i0, o), j1 = __shfl_xor(i1, o);
      bool f = (w0 < v0) || (w0 == v0 && j0 < i0);  // w-list wins head?
      float A0 = f ? w0 : v0, A1 = f ? w1 : v1, A2 = f ? w2 : v2;
      int  Ai0 = f ? j0 : i0, Ai1 = f ? j1 : i1;
      float B0 = f ? v0 : w0, B1 = f ? v1 : w1;
      int  Bi0 = f ? i0 : j0;
      bool g = (A1 < B0) || (A1 == B0 && Ai1 < Bi0);
      v0 = A0; i0 = Ai0;
      v1 = g ? A1 : B0; i1 = g ? Ai1 : Bi0;
      v2 = g ? fminf(A2, B0) : fminf(A1, B1);
    }
    if ((l >> 4) == 0)
      part[(size_t)slot * Ttok + tok0 + n * 16] = make_float4(
          v0, v1, __uint_as_float((unsigned)i0 | ((unsigned)i1 << 16)), v2);
  }
}

// exact fp32 rescore of one code (wave-cooperative), uniform n
__device__ inline void rescore(int n, const float4& xa, const float4& xb,
                               const float* __restrict__ cb,
                               const float* __restrict__ csq, int l,
                               float& bestv, int& besti) {
  const float4* cr = (const float4*)(cb + (size_t)n * Dd);
  float4 ca = cr[l * 2], cc = cr[l * 2 + 1];
  float p = xa.x*ca.x + xa.y*ca.y + xa.z*ca.z + xa.w*ca.w
          + xb.x*cc.x + xb.y*cc.y + xb.z*cc.z + xb.w*cc.w;
#pragma unroll
  for (int o = 32; o; o >>= 1) p += __shfl_xor(p, o);
  float sc = csq[n] - 2.0f * p;
  if (sc < bestv || (sc == bestv && n < besti)) { bestv = sc; besti = n; }
}

// exact rescore of a full 64-code half: one code per lane, then wave-argmin
__device__ inline void rescore_half(int h, const float* __restrict__ xrow,
                                    const float* __restrict__ cb,
                                    const float* __restrict__ csq, int l,
                                    float& bestv, int& besti) {
  int n = h * 64 + l;
  const float4* cr = (const float4*)(cb + (size_t)n * Dd);
  const float4* xr = (const float4*)xrow;
  float p = 0.f;
#pragma unroll 8
  for (int j = 0; j < 128; ++j) {
    float4 c4 = cr[j], x4 = xr[j];
    p += c4.x*x4.x + c4.y*x4.y + c4.z*x4.z + c4.w*x4.w;
  }
  float sc = csq[n] - 2.0f * p;
#pragma unroll
  for (int o = 1; o < 64; o <<= 1) {
    float ov = __shfl_xor(sc, o); int oi = __shfl_xor(n, o);
    if (ov < sc || (ov == sc && oi < n)) { sc = ov; n = oi; }
  }
  if (sc < bestv || (sc == bestv && n < besti)) { bestv = sc; besti = n; }
}

// ---- per-token: merge 16 half partials. FAST PATH: if the exact coarse
// runner-up g1 trails the min by > GAP, the coarse winner is provably the
// exact argmin (0 rescores, ~85% of tokens). Else rescore candidates <= m+GAP;
// a half needs full-64 rescore only if its v2 <= m+GAP (v2 bounds unstored).
__global__ __launch_bounds__(256) void k_select(
    const float4* __restrict__ part, const float* __restrict__ x,
    const float* __restrict__ cb, const float* __restrict__ csq,
    int* __restrict__ idxb, float* __restrict__ idxf, float* __restrict__ hist) {
  const int tid = threadIdx.x, wid = tid >> 6, l = tid & 63;
  const int t = blockIdx.x * 4 + wid;
  float v0 = 3.4e38f, v1 = 3.4e38f, v2 = 3.4e38f;
  int i0 = 0x7fffffff, i1 = 0x7fffffff;
  if (l < 16) {
    float4 e = part[(size_t)l * Ttok + t];
    v0 = e.x; v1 = e.y; v2 = e.w;
    unsigned ii = __float_as_uint(e.z);
    i0 = (int)(ii & 0xffff); i1 = (int)(ii >> 16);
  }
  // global top-2 via butterfly over the 16-lane group
  float A0 = v0, A1 = v1; int Ai0 = i0, Ai1 = i1;
#pragma unroll
  for (int o = 1; o < 16; o <<= 1) {
    float w0 = __shfl_xor(A0, o), w1 = __shfl_xor(A1, o);
    int  j0 = __shfl_xor(Ai0, o), j1 = __shfl_xor(Ai1, o);
    bool f = (w0 < A0) || (w0 == A0 && j0 < Ai0);
    float B0 = f ? A0 : w0; int Bi0 = f ? Ai0 : j0;     // loser head
    float W1 = f ? w1 : A1; int Wi1 = f ? j1 : Ai1;     // winner 2nd
    if (f) { A0 = w0; Ai0 = j0; }
    bool g = (B0 < W1) || (B0 == W1 && Bi0 < Wi1);
    A1 = g ? B0 : W1; Ai1 = g ? Bi0 : Wi1;
  }
  const float m  = __shfl(A0, 0);
  const float g1 = __shfl(A1, 0);
  const int   gi = __shfl(Ai0, 0);
  int besti;
  if (g1 - m > GAP) {
    besti = gi;                                  // provably exact, no loads
  } else {
    const float thr = m + GAP;
    const float* xrow = x + (size_t)t * Dd;
    const float4* xr = (const float4*)xrow;
    float4 xa = xr[l * 2], xb = xr[l * 2 + 1];
    float bestv = 3.4e38f; besti = 0x7fffffff;
    for (int h = 0; h < 16; ++h) {
      float b0 = __shfl(v0, h);
      if (b0 > thr) continue;
      float b1 = __shfl(v1, h), b2 = __shfl(v2, h);
      int bi0 = __shfl(i0, h), bi1 = __shfl(i1, h);
      if (b2 <= thr) {
        rescore_half(h, xrow, cb, csq, l, bestv, besti);   // rare
      } else {
        rescore(bi0, xa, xb, cb, csq, l, bestv, besti);
        if (b1 <= thr) rescore(bi1, xa, xb, cb, csq, l, bestv, besti);
      }
    }
  }
  if (l == 0) {
    idxb[t] = besti;
    idxf[t] = (float)besti;
    atomicAdd(&hist[besti], 1.0f);
  }
}

// ----------------- prefix sum of histogram (1 block, 256 thr, wave scan)
__global__ __launch_bounds__(256) void k_offsets(const float* __restrict__ hist,
                                                 int* __restrict__ offs,
                                                 int* __restrict__ cursor) {
  __shared__ int wsum[4];
  const int tid = threadIdx.x, l = tid & 63, wd = tid >> 6;
  const int base = tid * 4;
  int c0 = (int)hist[base], c1 = (int)hist[base + 1],
      c2 = (int)hist[base + 2], c3 = (int)hist[base + 3];
  int sum = c0 + c1 + c2 + c3;
  int sc = sum;
#pragma unroll
  for (int o = 1; o < 64; o <<= 1) { int v = __shfl_up(sc, o); if (l >= o) sc += v; }
  if (l == 63) wsum[wd] = sc;
  __syncthreads();
  int wbase = 0;
  for (int i = 0; i < wd; ++i) wbase += wsum[i];
  int e = wbase + sc - sum;
  offs[base] = e;     cursor[base] = e;
  offs[base+1] = e + c0; cursor[base+1] = e + c0;
  offs[base+2] = e + c0 + c1; cursor[base+2] = e + c0 + c1;
  offs[base+3] = e + c0 + c1 + c2; cursor[base+3] = e + c0 + c1 + c2;
}

// -------------------------------- bucket tokens by index (code-sorted order)
__global__ __launch_bounds__(256) void k_scatter(const int* __restrict__ idxb,
                                                 int* __restrict__ cursor,
                                                 int* __restrict__ bucket,
                                                 int* __restrict__ bcode) {
  int t = blockIdx.x * 256 + threadIdx.x;
  if (t < Ttok) {
    int n = idxb[t];
    int p = atomicAdd(&cursor[n], 1);
    bucket[p] = t;
    bcode[p] = n;
  }
}

// ------- load-balanced segmented sum: dw[n][d] += x rows of chunk segments
__global__ __launch_bounds__(512) void k_dw_part(
    const float* __restrict__ x, const int* __restrict__ bucket,
    const int* __restrict__ bcode, float* __restrict__ dw) {
  __shared__ int sh_t[CH], sh_n[CH];
  const int tid = threadIdx.x;
  const int p0 = blockIdx.x * CH;
  if (tid < CH) { sh_t[tid] = bucket[p0 + tid]; sh_n[tid] = bcode[p0 + tid]; }
  __syncthreads();
  float v[CH];
#pragma unroll
  for (int j = 0; j < CH; ++j)
    v[j] = x[(size_t)sh_t[j] * Dd + tid];
  float acc = v[0]; int cur = sh_n[0];
#pragma unroll
  for (int j = 1; j < CH; ++j) {
    int n = sh_n[j];
    if (n != cur) { atomicAdd(&dw[(size_t)cur * Dd + tid], acc); acc = 0.f; cur = n; }
    acc += v[j];
  }
  atomicAdd(&dw[(size_t)cur * Dd + tid], acc);
}

// -------- codebook_new = (decay*ema + (1-decay)*dw) / (decay*counts + (1-decay)*hist)
__global__ __launch_bounds__(256) void finalize_cb(
    const float* __restrict__ ema, const float* __restrict__ dw,
    const float* __restrict__ counts, const float* __restrict__ hist,
    float* __restrict__ cbnew) {
  int e4 = blockIdx.x * 256 + threadIdx.x;
  int n = e4 >> 7;
  float cnt = DECAYc * counts[n] + (1.0f - DECAYc) * hist[n];
  float inv = 1.0f / cnt;
  float4 e = ((const float4*)ema)[e4];
  float4 d = ((const float4*)dw)[e4];
  float4 o;
  o.x = (DECAYc * e.x + (1.0f - DECAYc) * d.x) * inv;
  o.y = (DECAYc * e.y + (1.0f - DECAYc) * d.y) * inv;
  o.z = (DECAYc * e.z + (1.0f - DECAYc) * d.z) * inv;
  o.w = (DECAYc * e.w + (1.0f - DECAYc) * d.w) * inv;
  ((float4*)cbnew)[e4] = o;
}

// ------- quantized = gather(cbnew, idx); loss partials (4-way ILP, r6)
__global__ __launch_bounds__(256) void quant_loss(
    const float* __restrict__ x, const float* __restrict__ cbnew,
    const int* __restrict__ idx, float* __restrict__ out_q,
    float* __restrict__ loss) {
  const int e0 = blockIdx.x * 256 + threadIdx.x;
  const int gsz = 524288;                    // 2048 blocks * 256 threads
  int n[4]; float4 q[4], xv[4];
#pragma unroll
  for (int j = 0; j < 4; ++j) n[j] = idx[(e0 + j * gsz) >> 7];
#pragma unroll
  for (int j = 0; j < 4; ++j) {
    const int e = e0 + j * gsz;
    q[j]  = ((const float4*)(cbnew + (size_t)n[j] * Dd))[e & 127];
    xv[j] = ((const float4*)x)[e];
  }
  float part = 0.f;
#pragma unroll
  for (int j = 0; j < 4; ++j) {
    ((float4*)out_q)[e0 + j * gsz] = q[j];
    float dx = xv[j].x - q[j].x, dy = xv[j].y - q[j].y,
          dz = xv[j].z - q[j].z, dw_ = xv[j].w - q[j].w;
    part += dx*dx + dy*dy + dz*dz + dw_*dw_;
  }
  __shared__ float red[4];
#pragma unroll
  for (int o = 32; o; o >>= 1) part += __shfl_down(part, o);
  int wid = threadIdx.x >> 6, lane = threadIdx.x & 63;
  if (lane == 0) red[wid] = part;
  __syncthreads();
  if (threadIdx.x == 0) atomicAdd(loss, red[0] + red[1] + red[2] + red[3]);
}

__global__ void loss_final(const float* __restrict__ loss,
                           float* __restrict__ out_loss) {
  *out_loss = loss[0] * (0.5f / (float)((size_t)Ttok * Dd));
}

// ---------------------------------------------------------------- launch
extern "C" void kernel_launch(void* const* d_in, const int* in_sizes, int n_in,
                              void* d_out, int out_size, void* d_ws, size_t ws_size,
                              hipStream_t stream) {
  const float* x      = (const float*)d_in[0];
  const float* cb     = (const float*)d_in[1];
  const float* ema    = (const float*)d_in[2];
  const float* counts = (const float*)d_in[3];

  float* out      = (float*)d_out;
  float* q_out    = out;
  float* loss_out = out + (size_t)Ttok * Dd;
  float* idxf_out = loss_out + 1;
  // per-half argmin partials (float4 [16][16384] = 4 MB) alias q_out's head;
  // fully consumed by k_select before quant_loss overwrites q_out.
  float4* part = (float4*)q_out;

  // workspace layout (float offsets) — same as r6/r8 (proven)
  float* ws = (float*)d_ws;
  unsigned short* cbh = (unsigned short*)ws;           // [0, 262144)  bf16 cb
  float* dw      = ws + 262144;                        // 524288 (zeroed)
  float* hist    = ws + 786432;                        // 1024   (zeroed)
  float* loss    = ws + 787456;                        // 4      (zeroed)
  float* csq     = ws + 787460;                        // 1024
  int*   offs    = (int*)(ws + 788484);                // 1024
  int*   cursor  = (int*)(ws + 789508);                // 1024
  int*   bucket  = (int*)(ws + 790532);                // 16384
  int*   bcode   = (int*)(ws + 806916);                // 16384
  int*   idxb    = (int*)(ws + 823300);                // 16384
  float* cbnew   = ws + 839684;                        // 524288 -> ends 1363972

  // zero dw + hist + loss (contiguous) every call
  hipMemsetAsync(dw, 0, (size_t)525316 * sizeof(float), stream);

  k_prep_cb<<<Nn, 64, 0, stream>>>(cb, cbh, csq);
  k_gemm_scores<<<(Nn / 128) * (Ttok / 128), 256, 0, stream>>>(cbh, x, csq, part);
  k_select<<<Ttok / 4, 256, 0, stream>>>(part, x, cb, csq, idxb, idxf_out, hist);
  k_offsets<<<1, 256, 0, stream>>>(hist, offs, cursor);
  k_scatter<<<Ttok / 256, 256, 0, stream>>>(idxb, cursor, bucket, bcode);
  k_dw_part<<<Ttok / CH, 512, 0, stream>>>(x, bucket, bcode, dw);
  finalize_cb<<<(Nn * Dd / 4) / 256, 256, 0, stream>>>(ema, dw, counts, hist, cbnew);
  quant_loss<<<2048, 256, 0, stream>>>(x, cbnew, idxb, q_out, loss);
  loss_final<<<1, 1, 0, stream>>>(loss, loss_out);
}

// Round 11
// 124.521 us; speedup vs baseline: 3.9824x; 1.0570x over previous
//
#include <hip/hip_runtime.h>
#include <hip/hip_bf16.h>

constexpr int Dd   = 512;
constexpr int Nn   = 1024;
constexpr int Ttok = 16384;              // B*L
constexpr float DECAYc = 0.99f;
// Coarse scores are f32 MFMA of bf16-rounded inputs: error std ~0.07.
// GAP=3.0 on the EXACT coarse runner-up (top-3 store makes g1 exact).
constexpr float GAP = 3.0f;
constexpr int CH = 16;                   // tokens per dw chunk

typedef short bf16x8 __attribute__((ext_vector_type(8)));
typedef float f32x4  __attribute__((ext_vector_type(4)));

__device__ inline unsigned cvtpk(float lo, float hi) { // 2xf32 -> packed bf16
  unsigned r;
  asm("v_cvt_pk_bf16_f32 %0, %1, %2" : "=v"(r) : "v"(lo), "v"(hi));
  return r;
}

// ---- fused prep: cb->bf16 + csq (blocks 0..255), zero dw/hist/loss
// (blocks 256..287), x->bf16 (blocks 288..2335, 2 chunks of 8 floats each)
constexpr int NB_CB = 256, NB_Z = 32, NB_X = 2048;
constexpr int ZF4 = 131329;              // float4s to zero (dw+hist+loss)
__global__ __launch_bounds__(256) void k_prep(
    const float* __restrict__ cb, const float* __restrict__ x,
    unsigned short* __restrict__ cbh, float* __restrict__ csq,
    unsigned short* __restrict__ xh, float4* __restrict__ zbase) {
  const int b = blockIdx.x, tid = threadIdx.x;
  if (b < NB_CB) {
    const int n = b * 4 + (tid >> 6), l = tid & 63;
    const float4* r = (const float4*)(cb + (size_t)n * Dd);
    float4 a = r[l], c = r[l + 64];
    float ss = a.x*a.x + a.y*a.y + a.z*a.z + a.w*a.w
             + c.x*c.x + c.y*c.y + c.z*c.z + c.w*c.w;
    uint2 ua, uc;
    ua.x = cvtpk(a.x, a.y); ua.y = cvtpk(a.z, a.w);
    uc.x = cvtpk(c.x, c.y); uc.y = cvtpk(c.z, c.w);
    ((uint2*)(cbh + (size_t)n * Dd))[l]      = ua;
    ((uint2*)(cbh + (size_t)n * Dd))[l + 64] = uc;
#pragma unroll
    for (int o = 32; o; o >>= 1) ss += __shfl_down(ss, o);
    if (l == 0) csq[n] = ss;
  } else if (b < NB_CB + NB_Z) {
    const float4 z = make_float4(0.f, 0.f, 0.f, 0.f);
    for (int i = (b - NB_CB) * 256 + tid; i < ZF4; i += NB_Z * 256)
      zbase[i] = z;
  } else {
    const int bx = b - (NB_CB + NB_Z);
#pragma unroll
    for (int k = 0; k < 2; ++k) {
      const int i = bx * 512 + k * 256 + tid;     // 8-float chunk id
      float4 a = ((const float4*)x)[i * 2];
      float4 c = ((const float4*)x)[i * 2 + 1];
      uint4 o;
      o.x = cvtpk(a.x, a.y); o.y = cvtpk(a.z, a.w);
      o.z = cvtpk(c.x, c.y); o.w = cvtpk(c.z, c.w);
      ((uint4*)xh)[i] = o;
    }
  }
}

// ------------- MFMA GEMM, both operands bf16 via global_load_lds with
// pre-swizzled global source, both double-buffered, ONE barrier per K-step.
// Fused per-64-code-half top-3 argmin epilogue (v0,v1,i0|i1,v2).
__global__ __launch_bounds__(256) void k_gemm_scores(
    const unsigned short* __restrict__ cbh, const unsigned short* __restrict__ xh,
    const float* __restrict__ csq, float4* __restrict__ part) {
  __shared__ unsigned short As[2][128 * 64];   // codes
  __shared__ unsigned short Bs[2][128 * 64];   // tokens
  const int tid = threadIdx.x;
  const int w = tid >> 6, l = tid & 63;
  const int b = blockIdx.x;
  const int s = (b & 7) * 128 + (b >> 3);      // XCD-aware bijective swizzle
  const int cm = s & 7;        // code-block  (M)
  const int tn = s >> 3;       // token-block (N)
  const int wr = w >> 1, wc = w & 1;

  const int srow = tid >> 3;                   // 0..31 staging row base
  const int xorw = (tid >> 3) & 7;             // row&7 of staged rows
  const int scol = ((tid & 7) ^ xorw) * 8;     // swizzled global source chunk

  f32x4 acc[4][4] = {};

  const unsigned short* gA0 = cbh + (size_t)(cm * 128) * Dd;
  const unsigned short* gB0 = xh  + (size_t)(tn * 128) * Dd;

#define ISSUE(KC, BUF) do {                                                   \
    const int k0_ = (KC) * 64;                                                \
    _Pragma("unroll")                                                         \
    for (int c = 0; c < 4; ++c) {                                             \
      const unsigned short* ga = gA0 + (size_t)(c * 32 + srow) * Dd + k0_ + scol; \
      const unsigned short* gb = gB0 + (size_t)(c * 32 + srow) * Dd + k0_ + scol; \
      char* la = (char*)&As[BUF][0] + c * 4096 + w * 1024;                    \
      char* lb = (char*)&Bs[BUF][0] + c * 4096 + w * 1024;                    \
      __builtin_amdgcn_global_load_lds((const __attribute__((address_space(1))) void*)ga, \
                                       (__attribute__((address_space(3))) void*)la, 16, 0, 0); \
      __builtin_amdgcn_global_load_lds((const __attribute__((address_space(1))) void*)gb, \
                                       (__attribute__((address_space(3))) void*)lb, 16, 0, 0); \
    }                                                                         \
  } while (0)

  ISSUE(0, 0);

  for (int kc = 0; kc < Dd / 64; ++kc) {
    __syncthreads();      // drains vmem -> tile kc ready; syncs buffer reuse
    if (kc + 1 < Dd / 64) ISSUE(kc + 1, (kc + 1) & 1);   // lands next barrier
    const unsigned short* Ab = &As[kc & 1][0];
    const unsigned short* Bb = &Bs[kc & 1][0];
#pragma unroll
    for (int ks = 0; ks < 2; ++ks) {
      const int ra = l & 15;
      const int rx = l & 7;
      const int kbs = ((ks * 4 + (l >> 4)) ^ rx) * 8;    // swizzled read chunk
      bf16x8 af[4], bfr[4];
#pragma unroll
      for (int m = 0; m < 4; ++m)
        af[m] = *(const bf16x8*)&Ab[(wr * 64 + m * 16 + ra) * 64 + kbs];
#pragma unroll
      for (int n = 0; n < 4; ++n)
        bfr[n] = *(const bf16x8*)&Bb[(wc * 64 + n * 16 + ra) * 64 + kbs];
#pragma unroll
      for (int m = 0; m < 4; ++m)
#pragma unroll
        for (int n = 0; n < 4; ++n)
          acc[m][n] = __builtin_amdgcn_mfma_f32_16x16x32_bf16(af[m], bfr[n], acc[m][n], 0, 0, 0);
    }
  }
#undef ISSUE

  // ------- fused per-half top-3 epilogue -------
  const int base4 = wr * 64 + (l >> 4) * 4;      // lane's local code base
  float4 cs[4];
#pragma unroll
  for (int m = 0; m < 4; ++m)
    cs[m] = *(const float4*)&csq[cm * 128 + base4 + m * 16];

  const int slot = cm * 2 + wr;                  // 0..15
  const int tok0 = tn * 128 + wc * 64 + (l & 15);

#pragma unroll
  for (int n = 0; n < 4; ++n) {
    float v0 = 3.4e38f, v1 = 3.4e38f, v2 = 3.4e38f;
    int i0 = 0x7fffffff, i1 = 0x7fffffff;
#pragma unroll
    for (int m = 0; m < 4; ++m) {
#pragma unroll
      for (int r = 0; r < 4; ++r) {
        float sv = fmaf(-2.0f, acc[m][n][r], ((const float*)&cs[m])[r]);
        int idx = cm * 128 + base4 + m * 16 + r;
        if (sv < v0)      { v2 = v1; v1 = v0; i1 = i0; v0 = sv; i0 = idx; }
        else if (sv < v1) { v2 = v1; v1 = sv; i1 = idx; }
        else if (sv < v2) { v2 = sv; }
      }
    }
#pragma unroll
    for (int o = 16; o <= 32; o <<= 1) {
      float w0 = __shfl_xor(v0, o), w1 = __shfl_xor(v1, o), w2 = __shfl_xor(v2, o);
      int  j0 = __shfl_xor(i0, o), j1 = __shfl_xor(i1, o);
      bool f = (w0 < v0) || (w0 == v0 && j0 < i0);
      float A0 = f ? w0 : v0, A1 = f ? w1 : v1, A2 = f ? w2 : v2;
      int  Ai0 = f ? j0 : i0, Ai1 = f ? j1 : i1;
      float B0 = f ? v0 : w0, B1 = f ? v1 : w1;
      int  Bi0 = f ? i0 : j0;
      bool g = (A1 < B0) || (A1 == B0 && Ai1 < Bi0);
      v0 = A0; i0 = Ai0;
      v1 = g ? A1 : B0; i1 = g ? Ai1 : Bi0;
      v2 = g ? fminf(A2, B0) : fminf(A1, B1);
    }
    if ((l >> 4) == 0)
      part[(size_t)slot * Ttok + tok0 + n * 16] = make_float4(
          v0, v1, __uint_as_float((unsigned)i0 | ((unsigned)i1 << 16)), v2);
  }
}

// exact fp32 rescore of one code (wave-cooperative), uniform n
__device__ inline void rescore(int n, const float4& xa, const float4& xb,
                               const float* __restrict__ cb,
                               const float* __restrict__ csq, int l,
                               float& bestv, int& besti) {
  const float4* cr = (const float4*)(cb + (size_t)n * Dd);
  float4 ca = cr[l * 2], cc = cr[l * 2 + 1];
  float p = xa.x*ca.x + xa.y*ca.y + xa.z*ca.z + xa.w*ca.w
          + xb.x*cc.x + xb.y*cc.y + xb.z*cc.z + xb.w*cc.w;
#pragma unroll
  for (int o = 32; o; o >>= 1) p += __shfl_xor(p, o);
  float sc = csq[n] - 2.0f * p;
  if (sc < bestv || (sc == bestv && n < besti)) { bestv = sc; besti = n; }
}

// exact rescore of a full 64-code half: one code per lane, then wave-argmin
__device__ inline void rescore_half(int h, const float* __restrict__ xrow,
                                    const float* __restrict__ cb,
                                    const float* __restrict__ csq, int l,
                                    float& bestv, int& besti) {
  int n = h * 64 + l;
  const float4* cr = (const float4*)(cb + (size_t)n * Dd);
  const float4* xr = (const float4*)xrow;
  float p = 0.f;
#pragma unroll 8
  for (int j = 0; j < 128; ++j) {
    float4 c4 = cr[j], x4 = xr[j];
    p += c4.x*x4.x + c4.y*x4.y + c4.z*x4.z + c4.w*x4.w;
  }
  float sc = csq[n] - 2.0f * p;
#pragma unroll
  for (int o = 1; o < 64; o <<= 1) {
    float ov = __shfl_xor(sc, o); int oi = __shfl_xor(n, o);
    if (ov < sc || (ov == sc && oi < n)) { sc = ov; n = oi; }
  }
  if (sc < bestv || (sc == bestv && n < besti)) { bestv = sc; besti = n; }
}

// ---- per-token: merge 16 half partials; fast path when exact coarse
// runner-up trails min by > GAP (no loads); else rescore candidates.
__global__ __launch_bounds__(256) void k_select(
    const float4* __restrict__ part, const float* __restrict__ x,
    const float* __restrict__ cb, const float* __restrict__ csq,
    int* __restrict__ idxb, float* __restrict__ idxf, float* __restrict__ hist) {
  const int tid = threadIdx.x, wid = tid >> 6, l = tid & 63;
  const int t = blockIdx.x * 4 + wid;
  float v0 = 3.4e38f, v1 = 3.4e38f, v2 = 3.4e38f;
  int i0 = 0x7fffffff, i1 = 0x7fffffff;
  if (l < 16) {
    float4 e = part[(size_t)l * Ttok + t];
    v0 = e.x; v1 = e.y; v2 = e.w;
    unsigned ii = __float_as_uint(e.z);
    i0 = (int)(ii & 0xffff); i1 = (int)(ii >> 16);
  }
  float A0 = v0, A1 = v1; int Ai0 = i0, Ai1 = i1;
#pragma unroll
  for (int o = 1; o < 16; o <<= 1) {
    float w0 = __shfl_xor(A0, o), w1 = __shfl_xor(A1, o);
    int  j0 = __shfl_xor(Ai0, o), j1 = __shfl_xor(Ai1, o);
    bool f = (w0 < A0) || (w0 == A0 && j0 < Ai0);
    float B0 = f ? A0 : w0; int Bi0 = f ? Ai0 : j0;
    float W1 = f ? w1 : A1; int Wi1 = f ? j1 : Ai1;
    if (f) { A0 = w0; Ai0 = j0; }
    bool g = (B0 < W1) || (B0 == W1 && Bi0 < Wi1);
    A1 = g ? B0 : W1; Ai1 = g ? Bi0 : Wi1;
  }
  const float m  = __shfl(A0, 0);
  const float g1 = __shfl(A1, 0);
  const int   gi = __shfl(Ai0, 0);
  int besti;
  if (g1 - m > GAP) {
    besti = gi;
  } else {
    const float thr = m + GAP;
    const float* xrow = x + (size_t)t * Dd;
    const float4* xr = (const float4*)xrow;
    float4 xa = xr[l * 2], xb = xr[l * 2 + 1];
    float bestv = 3.4e38f; besti = 0x7fffffff;
    for (int h = 0; h < 16; ++h) {
      float b0 = __shfl(v0, h);
      if (b0 > thr) continue;
      float b1 = __shfl(v1, h), b2 = __shfl(v2, h);
      int bi0 = __shfl(i0, h), bi1 = __shfl(i1, h);
      if (b2 <= thr) {
        rescore_half(h, xrow, cb, csq, l, bestv, besti);
      } else {
        rescore(bi0, xa, xb, cb, csq, l, bestv, besti);
        if (b1 <= thr) rescore(bi1, xa, xb, cb, csq, l, bestv, besti);
      }
    }
  }
  if (l == 0) {
    idxb[t] = besti;
    idxf[t] = (float)besti;
    atomicAdd(&hist[besti], 1.0f);
  }
}

// ----------------- prefix sum of histogram (1 block, 256 thr, wave scan)
__global__ __launch_bounds__(256) void k_offsets(const float* __restrict__ hist,
                                                 int* __restrict__ offs,
                                                 int* __restrict__ cursor) {
  __shared__ int wsum[4];
  const int tid = threadIdx.x, l = tid & 63, wd = tid >> 6;
  const int base = tid * 4;
  int c0 = (int)hist[base], c1 = (int)hist[base + 1],
      c2 = (int)hist[base + 2], c3 = (int)hist[base + 3];
  int sum = c0 + c1 + c2 + c3;
  int sc = sum;
#pragma unroll
  for (int o = 1; o < 64; o <<= 1) { int v = __shfl_up(sc, o); if (l >= o) sc += v; }
  if (l == 63) wsum[wd] = sc;
  __syncthreads();
  int wbase = 0;
  for (int i = 0; i < wd; ++i) wbase += wsum[i];
  int e = wbase + sc - sum;
  offs[base] = e;     cursor[base] = e;
  offs[base+1] = e + c0; cursor[base+1] = e + c0;
  offs[base+2] = e + c0 + c1; cursor[base+2] = e + c0 + c1;
  offs[base+3] = e + c0 + c1 + c2; cursor[base+3] = e + c0 + c1 + c2;
}

// -------------------------------- bucket tokens by index (code-sorted order)
__global__ __launch_bounds__(256) void k_scatter(const int* __restrict__ idxb,
                                                 int* __restrict__ cursor,
                                                 int* __restrict__ bucket,
                                                 int* __restrict__ bcode) {
  int t = blockIdx.x * 256 + threadIdx.x;
  if (t < Ttok) {
    int n = idxb[t];
    int p = atomicAdd(&cursor[n], 1);
    bucket[p] = t;
    bcode[p] = n;
  }
}

// ------- load-balanced segmented sum: dw[n][d] += x rows of chunk segments
__global__ __launch_bounds__(512) void k_dw_part(
    const float* __restrict__ x, const int* __restrict__ bucket,
    const int* __restrict__ bcode, float* __restrict__ dw) {
  __shared__ int sh_t[CH], sh_n[CH];
  const int tid = threadIdx.x;
  const int p0 = blockIdx.x * CH;
  if (tid < CH) { sh_t[tid] = bucket[p0 + tid]; sh_n[tid] = bcode[p0 + tid]; }
  __syncthreads();
  float v[CH];
#pragma unroll
  for (int j = 0; j < CH; ++j)
    v[j] = x[(size_t)sh_t[j] * Dd + tid];
  float acc = v[0]; int cur = sh_n[0];
#pragma unroll
  for (int j = 1; j < CH; ++j) {
    int n = sh_n[j];
    if (n != cur) { atomicAdd(&dw[(size_t)cur * Dd + tid], acc); acc = 0.f; cur = n; }
    acc += v[j];
  }
  atomicAdd(&dw[(size_t)cur * Dd + tid], acc);
}

// -------- codebook_new = (decay*ema + (1-decay)*dw) / (decay*counts + (1-decay)*hist)
__global__ __launch_bounds__(256) void finalize_cb(
    const float* __restrict__ ema, const float* __restrict__ dw,
    const float* __restrict__ counts, const float* __restrict__ hist,
    float* __restrict__ cbnew) {
  int e4 = blockIdx.x * 256 + threadIdx.x;
  int n = e4 >> 7;
  float cnt = DECAYc * counts[n] + (1.0f - DECAYc) * hist[n];
  float inv = 1.0f / cnt;
  float4 e = ((const float4*)ema)[e4];
  float4 d = ((const float4*)dw)[e4];
  float4 o;
  o.x = (DECAYc * e.x + (1.0f - DECAYc) * d.x) * inv;
  o.y = (DECAYc * e.y + (1.0f - DECAYc) * d.y) * inv;
  o.z = (DECAYc * e.z + (1.0f - DECAYc) * d.z) * inv;
  o.w = (DECAYc * e.w + (1.0f - DECAYc) * d.w) * inv;
  ((float4*)cbnew)[e4] = o;
}

// ------- quantized = gather(cbnew, idx); loss partials (4-way ILP, r6);
// nontemporal stores (via clang ext-vector f32x4 — HIP float4 is a class
// and __builtin_nontemporal_store rejects it) for the never-re-read q.
__global__ __launch_bounds__(256) void quant_loss(
    const float* __restrict__ x, const float* __restrict__ cbnew,
    const int* __restrict__ idx, float* __restrict__ out_q,
    float* __restrict__ loss) {
  const int e0 = blockIdx.x * 256 + threadIdx.x;
  const int gsz = 524288;                    // 2048 blocks * 256 threads
  int n[4]; f32x4 q[4], xv[4];
#pragma unroll
  for (int j = 0; j < 4; ++j) n[j] = idx[(e0 + j * gsz) >> 7];
#pragma unroll
  for (int j = 0; j < 4; ++j) {
    const int e = e0 + j * gsz;
    q[j]  = ((const f32x4*)(cbnew + (size_t)n[j] * Dd))[e & 127];
    xv[j] = ((const f32x4*)x)[e];
  }
  float part = 0.f;
#pragma unroll
  for (int j = 0; j < 4; ++j) {
    __builtin_nontemporal_store(q[j], &((f32x4*)out_q)[e0 + j * gsz]);
    f32x4 d = xv[j] - q[j];
    part += d[0]*d[0] + d[1]*d[1] + d[2]*d[2] + d[3]*d[3];
  }
  __shared__ float red[4];
#pragma unroll
  for (int o = 32; o; o >>= 1) part += __shfl_down(part, o);
  int wid = threadIdx.x >> 6, lane = threadIdx.x & 63;
  if (lane == 0) red[wid] = part;
  __syncthreads();
  if (threadIdx.x == 0) atomicAdd(loss, red[0] + red[1] + red[2] + red[3]);
}

__global__ void loss_final(const float* __restrict__ loss,
                           float* __restrict__ out_loss) {
  *out_loss = loss[0] * (0.5f / (float)((size_t)Ttok * Dd));
}

// ---------------------------------------------------------------- launch
extern "C" void kernel_launch(void* const* d_in, const int* in_sizes, int n_in,
                              void* d_out, int out_size, void* d_ws, size_t ws_size,
                              hipStream_t stream) {
  const float* x      = (const float*)d_in[0];
  const float* cb     = (const float*)d_in[1];
  const float* ema    = (const float*)d_in[2];
  const float* counts = (const float*)d_in[3];

  float* out      = (float*)d_out;
  float* q_out    = out;
  float* loss_out = out + (size_t)Ttok * Dd;
  float* idxf_out = loss_out + 1;
  // d_out head reuse before quant_loss overwrites it:
  //   part: float4[16][16384] = 4 MB at q_out[0 .. 1M floats)
  //   xh:   bf16 x (16.8 MB)   at q_out[2M .. 6.2M floats)   (no overlap)
  float4* part = (float4*)q_out;
  unsigned short* xh = (unsigned short*)(q_out + 2097152);

  // workspace layout (float offsets) — same as r6..r9 (proven)
  float* ws = (float*)d_ws;
  unsigned short* cbh = (unsigned short*)ws;           // [0, 262144)  bf16 cb
  float* dw      = ws + 262144;                        // 524288 (zeroed in k_prep)
  float* hist    = ws + 786432;                        // 1024   (zeroed in k_prep)
  float* loss    = ws + 787456;                        // 4      (zeroed in k_prep)
  float* csq     = ws + 787460;                        // 1024
  int*   offs    = (int*)(ws + 788484);                // 1024
  int*   cursor  = (int*)(ws + 789508);                // 1024
  int*   bucket  = (int*)(ws + 790532);                // 16384
  int*   bcode   = (int*)(ws + 806916);                // 16384
  int*   idxb    = (int*)(ws + 823300);                // 16384
  float* cbnew   = ws + 839684;                        // 524288 -> ends 1363972

  k_prep<<<NB_CB + NB_Z + NB_X, 256, 0, stream>>>(cb, x, cbh, csq, xh, (float4*)dw);
  k_gemm_scores<<<(Nn / 128) * (Ttok / 128), 256, 0, stream>>>(cbh, xh, csq, part);
  k_select<<<Ttok / 4, 256, 0, stream>>>(part, x, cb, csq, idxb, idxf_out, hist);
  k_offsets<<<1, 256, 0, stream>>>(hist, offs, cursor);
  k_scatter<<<Ttok / 256, 256, 0, stream>>>(idxb, cursor, bucket, bcode);
  k_dw_part<<<Ttok / CH, 512, 0, stream>>>(x, bucket, bcode, dw);
  finalize_cb<<<(Nn * Dd / 4) / 256, 256, 0, stream>>>(ema, dw, counts, hist, cbnew);
  quant_loss<<<2048, 256, 0, stream>>>(x, cbnew, idxb, q_out, loss);
  loss_final<<<1, 1, 0, stream>>>(loss, loss_out);
}